// Round 2
// baseline (8748.824 us; speedup 1.0000x reference)
//
#include <hip/hip_runtime.h>

typedef __bf16 bf16;
typedef __bf16 bf16x8 __attribute__((ext_vector_type(8)));
typedef __bf16 bf16x4 __attribute__((ext_vector_type(4)));
typedef float f32x4 __attribute__((ext_vector_type(4)));

// ---------------- workspace layout (bytes) ----------------
static constexpr size_t OFF_KT = 0;                          // kernel^T bf16 [2][3072][1024]
static constexpr size_t SZ_KT  = 2ull*3072*1024*2;
static constexpr size_t OFF_RT = OFF_KT + SZ_KT;             // rec^T bf16 [2][3072][1024]
static constexpr size_t SZ_RT  = SZ_KT;
static constexpr size_t OFF_XE = OFF_RT + SZ_RT;             // x_emb bf16 [t*64+b][1024]
static constexpr size_t SZ_XE  = 16384ull*1024*2;
static constexpr size_t OFF_XP = OFF_XE + SZ_XE;             // xp bf16 [d][j][t][g][b][16]
static constexpr size_t SZ_XP  = 2ull*16384*3072*2;
static constexpr size_t OFF_MASK = OFF_XP + SZ_XP;           // mask f32 [t][b]
static constexpr size_t SZ_MASK  = 16384ull*4;
static constexpr size_t OFF_HF = OFF_MASK + SZ_MASK;         // h fragments bf16, [d][parity]
static constexpr size_t HF_CHUNKS = 8448;                    // 8192 used + pad for staging
static constexpr size_t SZ_HF  = 4ull*HF_CHUNKS*16;
static constexpr size_t OFF_BAR = OFF_HF + SZ_HF;            // barrier {count, gen}

__device__ __forceinline__ void async16(void* lds, const void* g) {
  __builtin_amdgcn_global_load_lds((const __attribute__((address_space(1))) unsigned int*)g,
                                   (__attribute__((address_space(3))) unsigned int*)lds,
                                   16, 0, 0);
}

// ---------------- prep kernels ----------------
__global__ void zero_ws_k(char* ws) {
  size_t i = (size_t)blockIdx.x*256 + threadIdx.x;
  size_t n = (SZ_HF + 64)/16;
  if (i < n) ((uint4*)(ws + OFF_HF))[i] = make_uint4(0u,0u,0u,0u);
}

// f32 [1024][3072] -> bf16 [3072][1024] (n-major) for MFMA B-fragment loads
__global__ void transpose_cast_k(const float* kf, const float* kb,
                                 const float* rf, const float* rb, char* ws) {
  __shared__ float tile[32][33];
  const int mat = blockIdx.z;
  const float* src = (mat==0)?kf:(mat==1)?kb:(mat==2)?rf:rb;
  bf16* dst = (bf16*)(ws + ((mat<2)?OFF_KT:OFF_RT)) + (size_t)(mat&1)*3072*1024;
  const int k0 = blockIdx.x*32, n0 = blockIdx.y*32;
  const int r = threadIdx.x >> 5, c = threadIdx.x & 31;
  for (int rr = r; rr < 32; rr += 8)
    tile[rr][c] = src[(size_t)(k0+rr)*3072 + n0 + c];
  __syncthreads();
  const int rn = threadIdx.x >> 3, kq = threadIdx.x & 7;
  bf16x4 v;
  #pragma unroll
  for (int ii = 0; ii < 4; ++ii) v[ii] = (bf16)tile[kq*4+ii][rn];
  *(bf16x4*)(dst + (size_t)(n0+rn)*1024 + k0 + kq*4) = v;
}

__global__ void gather_xe_k(const int* x, const float* emb, char* ws) {
  size_t c = (size_t)blockIdx.x*256 + threadIdx.x;   // 16384*128 chunks of 8
  int rowid = (int)(c >> 7); int u8 = (int)(c & 127);
  int t = rowid >> 6, b = rowid & 63;
  int tok = x[b*256 + t];
  const float* e = emb + (size_t)tok*1024 + u8*8;
  float4 a  = *(const float4*)e;
  float4 b2 = *(const float4*)(e+4);
  bf16x8 o;
  o[0]=(bf16)a.x;  o[1]=(bf16)a.y;  o[2]=(bf16)a.z;  o[3]=(bf16)a.w;
  o[4]=(bf16)b2.x; o[5]=(bf16)b2.y; o[6]=(bf16)b2.z; o[7]=(bf16)b2.w;
  *(bf16x8*)((bf16*)(ws+OFF_XE) + (size_t)rowid*1024 + u8*8) = o;
}

__global__ void make_mask_k(const int* x, char* ws) {
  int tid = blockIdx.x*256 + threadIdx.x;            // t*64+b
  int t = tid >> 6, b = tid & 63;
  ((float*)(ws+OFF_MASK))[tid] = (x[b*256+t] != 0) ? 1.0f : 0.0f;
}

// ---------------- xp = xe @ kernel + b_i (both dirs), 128x128 tile ----------------
__global__ __launch_bounds__(256) void xp_gemm_k(const float* bias_f, const float* bias_b, char* ws) {
  __shared__ __align__(16) char smem[16384];         // As 128x32, Bs 128x32 bf16
  const int tid = threadIdx.x, w = tid>>6, l = tid&63;
  const int m0 = blockIdx.x*128, n0 = blockIdx.y*128, d = blockIdx.z;
  const bf16* xe = (const bf16*)(ws + OFF_XE);
  const bf16* Bt = (const bf16*)(ws + OFF_KT) + (size_t)d*3072*1024;
  const float* bias = d ? bias_b : bias_f;           // row 0 = b_i
  const int wm = (w>>1)*64, wn = (w&1)*64;
  const f32x4 fzero = {0.f,0.f,0.f,0.f};
  f32x4 acc[4][4];
  #pragma unroll
  for (int i=0;i<4;++i)
    #pragma unroll
    for (int jj=0;jj<4;++jj) acc[i][jj] = fzero;
  for (int k0 = 0; k0 < 1024; k0 += 32) {
    #pragma unroll
    for (int it = 0; it < 2; ++it) {
      int cc = w*128 + it*64 + l;                    // 0..511
      int row = cc>>2, kp = cc&3;
      async16(smem        + (size_t)(w*128 + it*64)*16, xe + (size_t)(m0+row)*1024 + k0 + kp*8);
      async16(smem + 8192 + (size_t)(w*128 + it*64)*16, Bt + (size_t)(n0+row)*1024 + k0 + kp*8);
    }
    __builtin_amdgcn_s_waitcnt(0);
    __syncthreads();
    const bf16* As = (const bf16*)smem;
    const bf16* Bs = (const bf16*)(smem + 8192);
    bf16x8 bfr[4];
    #pragma unroll
    for (int nt=0;nt<4;++nt)
      bfr[nt] = *(const bf16x8*)(Bs + (wn + nt*16 + (l&15))*32 + (l>>4)*8);
    #pragma unroll
    for (int mt=0;mt<4;++mt) {
      bf16x8 af = *(const bf16x8*)(As + (wm + mt*16 + (l&15))*32 + (l>>4)*8);
      #pragma unroll
      for (int nt=0;nt<4;++nt)
        acc[mt][nt] = __builtin_amdgcn_mfma_f32_16x16x32_bf16(af, bfr[nt], acc[mt][nt], 0,0,0);
    }
    __syncthreads();
  }
  bf16* xp = (bf16*)(ws + OFF_XP);
  #pragma unroll
  for (int nt=0;nt<4;++nt) {
    int n = n0 + wn + nt*16 + (l&15);
    float bv = bias[n];
    int g = n>>10, jj = (n>>4)&63, u = n&15;
    #pragma unroll
    for (int mt=0;mt<4;++mt) {
      #pragma unroll
      for (int r2=0;r2<4;++r2) {
        int m = m0 + wm + mt*16 + (l>>4)*4 + r2;
        int t = m>>6, b = m&63;
        float val = acc[mt][nt][r2] + bv;
        xp[((((size_t)(d*64+jj)*256 + t)*3 + g)*64 + b)*16 + u] = (bf16)val;
      }
    }
  }
}

// ---------------- persistent GRU scan ----------------
__device__ __forceinline__ void grid_barrier(unsigned* bar, unsigned* lgen, int nblk) {
  __syncthreads();
  if (threadIdx.x == 0) {
    __threadfence();   // device-scope release (L2 writeback)
    unsigned g = *lgen;
    unsigned a = __hip_atomic_fetch_add(&bar[0], 1u, __ATOMIC_ACQ_REL, __HIP_MEMORY_SCOPE_AGENT);
    if (a == (unsigned)(nblk - 1)) {
      __hip_atomic_store(&bar[0], 0u,    __ATOMIC_RELAXED, __HIP_MEMORY_SCOPE_AGENT);
      __hip_atomic_store(&bar[1], g+1u,  __ATOMIC_RELEASE, __HIP_MEMORY_SCOPE_AGENT);
    } else {
      while (__hip_atomic_load(&bar[1], __ATOMIC_RELAXED, __HIP_MEMORY_SCOPE_AGENT) == g)
        __builtin_amdgcn_s_sleep(2);
    }
    __builtin_amdgcn_fence(__ATOMIC_ACQUIRE, "agent");
    *lgen = g + 1u;
  }
  __syncthreads();
}

// 128 WGs: wg = d*64 + j (j = 16-unit block). 3 waves = K-split 11/11/10 ktiles,
// each wave holds B-frags for all 3 gates of its K-slice in VGPRs (33 x bf16x8).
__global__ __launch_bounds__(192, 1) void gru_scan_k(char* ws, float* out,
                                                     const float* bias_f, const float* bias_b) {
  __shared__ __align__(16) char lds_h[8256*16];      // h fragments (132 KB)
  __shared__ float rec_lds[3*1024];                  // [g][b][u16] partial sums (+b_r)
  __shared__ float h_master[1024];                   // f32 h state for this unit block
  __shared__ float br_lds[48];
  const int wg = blockIdx.x;
  const int d = wg >> 6, j = wg & 63;
  const int tid = threadIdx.x, w = tid >> 6, l = tid & 63;
  const bf16* rT   = (const bf16*)(ws + OFF_RT) + (size_t)d*3072*1024;
  const bf16* xp   = (const bf16*)(ws + OFF_XP);
  const float* mask = (const float*)(ws + OFF_MASK);
  bf16* hf = (bf16*)(ws + OFF_HF);
  unsigned* bar = (unsigned*)(ws + OFF_BAR);
  const float* bias = d ? bias_b : bias_f;
  if (tid < 48) br_lds[tid] = bias[3072 + (tid>>4)*1024 + j*16 + (tid&15)];   // b_r
  for (int p = tid; p < 1024; p += 192) h_master[p] = 0.f;
  const int kt0 = w*11;
  const int ktn = (w < 2) ? 11 : 10;
  bf16x8 Breg[33];                                   // [gate][kk]
  #pragma unroll
  for (int g = 0; g < 3; ++g)
    #pragma unroll
    for (int kk = 0; kk < 11; ++kk)
      if (kk < ktn)
        Breg[g*11+kk] = *(const bf16x8*)(rT + (size_t)(g*1024 + j*16 + (l&15))*1024
                                            + (kt0+kk)*32 + (l>>4)*8);
  __syncthreads();
  unsigned lgen = 0;
  const f32x4 fzero = {0.f,0.f,0.f,0.f};
  for (int step = 0; step < 256; ++step) {
    const int t = d ? (255 - step) : step;
    // ---- stage h fragments (current parity) into LDS; init rec_lds = b_r meanwhile
    const bf16* hsrc = hf + (size_t)(d*2 + (step&1))*HF_CHUNKS*8;
    for (int i = 0; i < 43; ++i)
      async16(lds_h + (size_t)(i*192 + w*64)*16, hsrc + (size_t)(i*192 + w*64 + l)*8);
    for (int p = tid; p < 3072; p += 192)
      rec_lds[p] = br_lds[((p>>10)<<4) | (p&15)];
    __builtin_amdgcn_s_waitcnt(0);
    __syncthreads();
    // ---- GEMM: rec[b][gate-cols] partials over this wave's K-slice
    f32x4 acc[4][3];
    #pragma unroll
    for (int mt=0;mt<4;++mt)
      #pragma unroll
      for (int g=0;g<3;++g) acc[mt][g] = fzero;
    #pragma unroll
    for (int kk = 0; kk < 11; ++kk) {
      if (kk < ktn) {
        const int kt = kt0 + kk;
        #pragma unroll
        for (int mt = 0; mt < 4; ++mt) {
          bf16x8 a = *(const bf16x8*)(lds_h + (size_t)((kt*4 + mt)*64 + l)*16);
          acc[mt][0] = __builtin_amdgcn_mfma_f32_16x16x32_bf16(a, Breg[0*11+kk], acc[mt][0],0,0,0);
          acc[mt][1] = __builtin_amdgcn_mfma_f32_16x16x32_bf16(a, Breg[1*11+kk], acc[mt][1],0,0,0);
          acc[mt][2] = __builtin_amdgcn_mfma_f32_16x16x32_bf16(a, Breg[2*11+kk], acc[mt][2],0,0,0);
        }
      }
    }
    #pragma unroll
    for (int mt = 0; mt < 4; ++mt)
      #pragma unroll
      for (int g = 0; g < 3; ++g)
        #pragma unroll
        for (int r2 = 0; r2 < 4; ++r2) {
          int b = mt*16 + (l>>4)*4 + r2;
          atomicAdd(&rec_lds[g*1024 + b*16 + (l&15)], acc[mt][g][r2]);
        }
    __syncthreads();
    // ---- gate fusion + h update + output + next-step fragment write
    bf16* hdst = hf + (size_t)(d*2 + ((step+1)&1))*HF_CHUNKS*8;
    const bf16* xpt = xp + (((size_t)(d*64 + j)*256 + t)*3)*1024;   // [g][b][u]
    const bool mystore = d ? (t >= 128) : (t < 128);
    for (int p = tid; p < 1024; p += 192) {
      int b = p >> 4, u = p & 15;
      float xz = (float)xpt[p];
      float xr = (float)xpt[1024 + p];
      float xh = (float)xpt[2048 + p];
      float z = 1.f/(1.f + __expf(-(xz + rec_lds[p])));
      float r = 1.f/(1.f + __expf(-(xr + rec_lds[1024 + p])));
      float pre = xh + r*rec_lds[2048 + p];
      pre = fminf(fmaxf(pre, -15.f), 15.f);
      float e2 = __expf(-2.f*pre);
      float hh = (1.f - e2)/(1.f + e2);
      float hold = h_master[p];
      float hnew = z*hold + (1.f - z)*hh;
      float m = mask[t*64 + b];
      float ho = (m != 0.f) ? hnew : hold;
      h_master[p] = ho;
      size_t oaddr = ((size_t)b*256 + t)*1024 + j*16 + u;
      if (mystore) out[oaddr] = ho;
      else         out[oaddr] += ho;       // earlier phase already stored; barriers order it
      int Ug = j*16 + u, kt = Ug>>5, kk2 = Ug&31, mt = b>>4;
      int lw = (b&15) | ((kk2>>3)<<4);
      hdst[(size_t)((kt*4+mt)*64 + lw)*8 + (kk2&7)] = (bf16)ho;
    }
    if (step < 255) grid_barrier(bar, &lgen, 128);
  }
}

// ---------------- launch ----------------
extern "C" void kernel_launch(void* const* d_in, const int* in_sizes, int n_in,
                              void* d_out, int out_size, void* d_ws, size_t ws_size,
                              hipStream_t stream) {
  (void)in_sizes; (void)n_in; (void)out_size; (void)ws_size;
  const int*   x   = (const int*)d_in[0];
  const float* emb = (const float*)d_in[1];
  const float* kf  = (const float*)d_in[2];
  const float* rf  = (const float*)d_in[3];
  const float* bf_ = (const float*)d_in[4];
  const float* kb  = (const float*)d_in[5];
  const float* rb  = (const float*)d_in[6];
  const float* bb  = (const float*)d_in[7];
  char* ws = (char*)d_ws;
  float* out = (float*)d_out;
  zero_ws_k<<<133, 256, 0, stream>>>(ws);
  transpose_cast_k<<<dim3(32,96,4), 256, 0, stream>>>(kf, kb, rf, rb, ws);
  gather_xe_k<<<8192, 256, 0, stream>>>(x, emb, ws);
  make_mask_k<<<64, 256, 0, stream>>>(x, ws);
  xp_gemm_k<<<dim3(128,24,2), 256, 0, stream>>>(bf_, bb, ws);
  gru_scan_k<<<128, 192, 0, stream>>>(ws, out, bf_, bb);
}

// Round 3
// 7535.991 us; speedup vs baseline: 1.1609x; 1.1609x over previous
//
#include <hip/hip_runtime.h>

typedef __bf16 bf16;
typedef __bf16 bf16x8 __attribute__((ext_vector_type(8)));
typedef __bf16 bf16x4 __attribute__((ext_vector_type(4)));
typedef float f32x4 __attribute__((ext_vector_type(4)));

// ---------------- workspace layout (bytes) ----------------
// Persistent: RT, XP, MASK, BAR, RING. KT/XE are prep-only and overlay the ring.
static constexpr size_t SZ_RT   = 2ull*3072*1024*2;          // rec^T bf16 [2][3072][1024]
static constexpr size_t SZ_XP   = 2ull*16384*3072*2;         // xp bf16 [d][j][t][g][b][16]
static constexpr size_t SZ_MASK = 16384ull*4;                // mask f32 [t][b]
static constexpr size_t HF_CHUNKS = 8256;                    // 8192 used + staging pad (43*192)
static constexpr size_t SLOT    = 2ull*HF_CHUNKS*16;         // one ring slot = [d][8256 chunks]
static constexpr size_t OFF_RT   = 0;
static constexpr size_t OFF_XP   = OFF_RT + SZ_RT;
static constexpr size_t OFF_MASK = OFF_XP + SZ_XP;
static constexpr size_t OFF_BAR  = OFF_MASK + SZ_MASK;
static constexpr size_t OFF_RING = OFF_BAR + 256;            // 257 slots (write-once per call)
static constexpr size_t OFF_KT   = OFF_RING;                 // prep-only (dead before ring use)
static constexpr size_t OFF_XE   = OFF_RING + 2ull*3072*1024*2;

__device__ __forceinline__ void async16(void* lds, const void* g) {
  __builtin_amdgcn_global_load_lds((const __attribute__((address_space(1))) unsigned int*)g,
                                   (__attribute__((address_space(3))) unsigned int*)lds,
                                   16, 0, 0);
}

// ---------------- prep kernels ----------------
// Runs AFTER xp_gemm (overlays KT): zero ring slot 0 (initial h) + barrier counter.
__global__ void zero_ws_k(char* ws) {
  size_t i = (size_t)blockIdx.x*256 + threadIdx.x;
  if (i < SLOT/16)                 ((uint4*)(ws + OFF_RING))[i] = make_uint4(0u,0u,0u,0u);
  else if (i < SLOT/16 + 16)       ((uint4*)(ws + OFF_BAR))[i - SLOT/16] = make_uint4(0u,0u,0u,0u);
}

// f32 [1024][3072] -> bf16 [3072][1024] (n-major) for MFMA B-fragment loads
__global__ void transpose_cast_k(const float* kf, const float* kb,
                                 const float* rf, const float* rb, char* ws) {
  __shared__ float tile[32][33];
  const int mat = blockIdx.z;
  const float* src = (mat==0)?kf:(mat==1)?kb:(mat==2)?rf:rb;
  bf16* dst = (bf16*)(ws + ((mat<2)?OFF_KT:OFF_RT)) + (size_t)(mat&1)*3072*1024;
  const int k0 = blockIdx.x*32, n0 = blockIdx.y*32;
  const int r = threadIdx.x >> 5, c = threadIdx.x & 31;
  for (int rr = r; rr < 32; rr += 8)
    tile[rr][c] = src[(size_t)(k0+rr)*3072 + n0 + c];
  __syncthreads();
  const int rn = threadIdx.x >> 3, kq = threadIdx.x & 7;
  bf16x4 v;
  #pragma unroll
  for (int ii = 0; ii < 4; ++ii) v[ii] = (bf16)tile[kq*4+ii][rn];
  *(bf16x4*)(dst + (size_t)(n0+rn)*1024 + k0 + kq*4) = v;
}

__global__ void gather_xe_k(const int* x, const float* emb, char* ws) {
  size_t c = (size_t)blockIdx.x*256 + threadIdx.x;   // 16384*128 chunks of 8
  int rowid = (int)(c >> 7); int u8 = (int)(c & 127);
  int t = rowid >> 6, b = rowid & 63;
  int tok = x[b*256 + t];
  const float* e = emb + (size_t)tok*1024 + u8*8;
  float4 a  = *(const float4*)e;
  float4 b2 = *(const float4*)(e+4);
  bf16x8 o;
  o[0]=(bf16)a.x;  o[1]=(bf16)a.y;  o[2]=(bf16)a.z;  o[3]=(bf16)a.w;
  o[4]=(bf16)b2.x; o[5]=(bf16)b2.y; o[6]=(bf16)b2.z; o[7]=(bf16)b2.w;
  *(bf16x8*)((bf16*)(ws+OFF_XE) + (size_t)rowid*1024 + u8*8) = o;
}

__global__ void make_mask_k(const int* x, char* ws) {
  int tid = blockIdx.x*256 + threadIdx.x;            // t*64+b
  int t = tid >> 6, b = tid & 63;
  ((float*)(ws+OFF_MASK))[tid] = (x[b*256+t] != 0) ? 1.0f : 0.0f;
}

// ---------------- xp = xe @ kernel + b_i (both dirs), 128x128 tile ----------------
__global__ __launch_bounds__(256) void xp_gemm_k(const float* bias_f, const float* bias_b, char* ws) {
  __shared__ __align__(16) char smem[16384];         // As 128x32, Bs 128x32 bf16
  const int tid = threadIdx.x, w = tid>>6, l = tid&63;
  const int m0 = blockIdx.x*128, n0 = blockIdx.y*128, d = blockIdx.z;
  const bf16* xe = (const bf16*)(ws + OFF_XE);
  const bf16* Bt = (const bf16*)(ws + OFF_KT) + (size_t)d*3072*1024;
  const float* bias = d ? bias_b : bias_f;           // row 0 = b_i
  const int wm = (w>>1)*64, wn = (w&1)*64;
  const f32x4 fzero = {0.f,0.f,0.f,0.f};
  f32x4 acc[4][4];
  #pragma unroll
  for (int i=0;i<4;++i)
    #pragma unroll
    for (int jj=0;jj<4;++jj) acc[i][jj] = fzero;
  for (int k0 = 0; k0 < 1024; k0 += 32) {
    #pragma unroll
    for (int it = 0; it < 2; ++it) {
      int cc = w*128 + it*64 + l;                    // 0..511
      int row = cc>>2, kp = cc&3;
      async16(smem        + (size_t)(w*128 + it*64)*16, xe + (size_t)(m0+row)*1024 + k0 + kp*8);
      async16(smem + 8192 + (size_t)(w*128 + it*64)*16, Bt + (size_t)(n0+row)*1024 + k0 + kp*8);
    }
    __builtin_amdgcn_s_waitcnt(0);
    __syncthreads();
    const bf16* As = (const bf16*)smem;
    const bf16* Bs = (const bf16*)(smem + 8192);
    bf16x8 bfr[4];
    #pragma unroll
    for (int nt=0;nt<4;++nt)
      bfr[nt] = *(const bf16x8*)(Bs + (wn + nt*16 + (l&15))*32 + (l>>4)*8);
    #pragma unroll
    for (int mt=0;mt<4;++mt) {
      bf16x8 af = *(const bf16x8*)(As + (wm + mt*16 + (l&15))*32 + (l>>4)*8);
      #pragma unroll
      for (int nt=0;nt<4;++nt)
        acc[mt][nt] = __builtin_amdgcn_mfma_f32_16x16x32_bf16(af, bfr[nt], acc[mt][nt], 0,0,0);
    }
    __syncthreads();
  }
  bf16* xp = (bf16*)(ws + OFF_XP);
  #pragma unroll
  for (int nt=0;nt<4;++nt) {
    int n = n0 + wn + nt*16 + (l&15);
    float bv = bias[n];
    int g = n>>10, jj = (n>>4)&63, u = n&15;
    #pragma unroll
    for (int mt=0;mt<4;++mt) {
      #pragma unroll
      for (int r2=0;r2<4;++r2) {
        int m = m0 + wm + mt*16 + (l>>4)*4 + r2;
        int t = m>>6, b = m&63;
        float val = acc[mt][nt][r2] + bv;
        xp[((((size_t)(d*64+jj)*256 + t)*3 + g)*64 + b)*16 + u] = (bf16)val;
      }
    }
  }
}

// ---------------- persistent GRU scan ----------------
// Monotonic-counter grid barrier: no fences, no cache maintenance. Ordering:
// __syncthreads drains each wave's vmem (sc1 stores reach LLC) before thread0's
// fetch_add; pollers only proceed once ALL 128 WGs have incremented.
__device__ __forceinline__ void grid_barrier(unsigned* bar, unsigned* lgen) {
  __builtin_amdgcn_s_waitcnt(0);
  __syncthreads();
  if (threadIdx.x == 0) {
    unsigned target = (*lgen += 128u);
    unsigned a = __hip_atomic_fetch_add(bar, 1u, __ATOMIC_RELAXED, __HIP_MEMORY_SCOPE_AGENT);
    if (a != target - 1u) {
      while (__hip_atomic_load(bar, __ATOMIC_RELAXED, __HIP_MEMORY_SCOPE_AGENT) < target)
        __builtin_amdgcn_s_sleep(8);
    }
  }
  __syncthreads();
}

// 128 WGs: wg = d*64 + j (j = 16-unit block). 3 waves = K-split 11/11/10 ktiles,
// rec_kernel B-frags pinned in VGPRs. h broadcast through a write-once ring:
// slot s holds h after step s-1; writes are agent-scope (LLC write-through),
// reads are plain cached global_load_lds (safe: every address written once,
// before any read, and never rewritten this call).
__global__ __launch_bounds__(192, 1) void gru_scan_k(char* ws, float* out,
                                                     const float* bias_f, const float* bias_b) {
  __shared__ __align__(16) char lds_h[HF_CHUNKS*16];  // h fragments (132 KB)
  __shared__ float rec_lds[3*1024];                   // [g][b][u16] partial sums (+b_r)
  __shared__ float h_master[1024];                    // f32 h state for this unit block
  __shared__ float br_lds[48];
  const int wg = blockIdx.x;
  const int d = wg >> 6, j = wg & 63;
  const int tid = threadIdx.x, w = tid >> 6, l = tid & 63;
  const bf16* rT    = (const bf16*)(ws + OFF_RT) + (size_t)d*3072*1024;
  const bf16* xp    = (const bf16*)(ws + OFF_XP);
  const float* mask = (const float*)(ws + OFF_MASK);
  char* ring = ws + OFF_RING;
  unsigned* bar = (unsigned*)(ws + OFF_BAR);
  const float* bias = d ? bias_b : bias_f;
  if (tid < 48) br_lds[tid] = bias[3072 + (tid>>4)*1024 + j*16 + (tid&15)];   // b_r
  for (int p = tid; p < 1024; p += 192) h_master[p] = 0.f;
  const int kt0 = w*11;
  const int ktn = (w < 2) ? 11 : 10;
  bf16x8 Breg[33];                                    // [gate][kk]
  #pragma unroll
  for (int g = 0; g < 3; ++g)
    #pragma unroll
    for (int kk = 0; kk < 11; ++kk)
      if (kk < ktn)
        Breg[g*11+kk] = *(const bf16x8*)(rT + (size_t)(g*1024 + j*16 + (l&15))*1024
                                            + (kt0+kk)*32 + (l>>4)*8);
  __syncthreads();
  unsigned lgen = 0;
  const f32x4 fzero = {0.f,0.f,0.f,0.f};
  for (int step = 0; step < 256; ++step) {
    const int t = d ? (255 - step) : step;
    // ---- stage h fragments (ring slot = step) into LDS; init rec_lds = b_r meanwhile
    const char* hsrc = ring + (size_t)step*SLOT + (size_t)d*(SLOT/2);
    for (int i = 0; i < 43; ++i)
      async16(lds_h + (size_t)(i*192 + w*64)*16, hsrc + (size_t)(i*192 + w*64 + l)*16);
    for (int p = tid; p < 3072; p += 192)
      rec_lds[p] = br_lds[((p>>10)<<4) | (p&15)];
    __builtin_amdgcn_s_waitcnt(0);
    __syncthreads();
    // ---- GEMM: rec[b][gate-cols] partials over this wave's K-slice
    f32x4 acc[4][3];
    #pragma unroll
    for (int mt=0;mt<4;++mt)
      #pragma unroll
      for (int g=0;g<3;++g) acc[mt][g] = fzero;
    #pragma unroll
    for (int kk = 0; kk < 11; ++kk) {
      if (kk < ktn) {
        const int kt = kt0 + kk;
        #pragma unroll
        for (int mt = 0; mt < 4; ++mt) {
          bf16x8 a = *(const bf16x8*)(lds_h + (size_t)((kt*4 + mt)*64 + l)*16);
          acc[mt][0] = __builtin_amdgcn_mfma_f32_16x16x32_bf16(a, Breg[0*11+kk], acc[mt][0],0,0,0);
          acc[mt][1] = __builtin_amdgcn_mfma_f32_16x16x32_bf16(a, Breg[1*11+kk], acc[mt][1],0,0,0);
          acc[mt][2] = __builtin_amdgcn_mfma_f32_16x16x32_bf16(a, Breg[2*11+kk], acc[mt][2],0,0,0);
        }
      }
    }
    #pragma unroll
    for (int mt = 0; mt < 4; ++mt)
      #pragma unroll
      for (int g = 0; g < 3; ++g)
        #pragma unroll
        for (int r2 = 0; r2 < 4; ++r2) {
          int b = mt*16 + (l>>4)*4 + r2;
          atomicAdd(&rec_lds[g*1024 + b*16 + (l&15)], acc[mt][g][r2]);
        }
    __syncthreads();
    // ---- gate fusion + h update + output + next-slot fragment write
    bf16* hdst = (bf16*)(ring + (size_t)(step+1)*SLOT + (size_t)d*(SLOT/2));
    const bf16* xpt = xp + (((size_t)(d*64 + j)*256 + t)*3)*1024;   // [g][b][u]
    const bool adder = d ? (t < 128) : (t >= 128);    // later phase adds
    if (tid < 128) {
      const int b = tid >> 1, half = tid & 1, u0 = half*8;
      bf16x8 xzv = *(const bf16x8*)(xpt + b*16 + u0);
      bf16x8 xrv = *(const bf16x8*)(xpt + 1024 + b*16 + u0);
      bf16x8 xhv = *(const bf16x8*)(xpt + 2048 + b*16 + u0);
      const float m = mask[t*64 + b];
      float hvals[8];
      #pragma unroll
      for (int i = 0; i < 8; ++i) {
        int p = b*16 + u0 + i;
        float z = 1.f/(1.f + __expf(-((float)xzv[i] + rec_lds[p])));
        float r = 1.f/(1.f + __expf(-((float)xrv[i] + rec_lds[1024 + p])));
        float pre = (float)xhv[i] + r*rec_lds[2048 + p];
        pre = fminf(fmaxf(pre, -15.f), 15.f);
        float e2 = __expf(-2.f*pre);
        float hh = (1.f - e2)/(1.f + e2);
        float hold = h_master[p];
        float hnew = z*hold + (1.f - z)*hh;
        float ho = (m != 0.f) ? hnew : hold;
        h_master[p] = ho;
        hvals[i] = ho;
      }
      float* op = out + ((size_t)b*256 + t)*1024 + j*16 + u0;
      if (adder) {
        #pragma unroll
        for (int i = 0; i < 8; ++i) {
          float prev = __hip_atomic_load(op + i, __ATOMIC_RELAXED, __HIP_MEMORY_SCOPE_AGENT);
          __hip_atomic_store(op + i, prev + hvals[i], __ATOMIC_RELAXED, __HIP_MEMORY_SCOPE_AGENT);
        }
      } else {
        #pragma unroll
        for (int i = 0; i < 8; ++i)
          __hip_atomic_store(op + i, hvals[i], __ATOMIC_RELAXED, __HIP_MEMORY_SCOPE_AGENT);
      }
      // h-fragment chunk for next step (16B = 8 bf16, MFMA A-layout)
      const int kt = j >> 1, q = (j&1)*2 + half, lw = (b&15) | (q<<4), mt = b>>4;
      union { bf16 h8[8]; unsigned long long q2[2]; } pk;
      #pragma unroll
      for (int i = 0; i < 8; ++i) pk.h8[i] = (bf16)hvals[i];
      unsigned long long* hq = (unsigned long long*)(hdst + (size_t)((kt*4 + mt)*64 + lw)*8);
      __hip_atomic_store(hq,     pk.q2[0], __ATOMIC_RELAXED, __HIP_MEMORY_SCOPE_AGENT);
      __hip_atomic_store(hq + 1, pk.q2[1], __ATOMIC_RELAXED, __HIP_MEMORY_SCOPE_AGENT);
    }
    if (step < 255) grid_barrier(bar, &lgen);
  }
}

// ---------------- launch ----------------
extern "C" void kernel_launch(void* const* d_in, const int* in_sizes, int n_in,
                              void* d_out, int out_size, void* d_ws, size_t ws_size,
                              hipStream_t stream) {
  (void)in_sizes; (void)n_in; (void)out_size; (void)ws_size;
  const int*   x   = (const int*)d_in[0];
  const float* emb = (const float*)d_in[1];
  const float* kf  = (const float*)d_in[2];
  const float* rf  = (const float*)d_in[3];
  const float* bf_ = (const float*)d_in[4];
  const float* kb  = (const float*)d_in[5];
  const float* rb  = (const float*)d_in[6];
  const float* bb  = (const float*)d_in[7];
  char* ws = (char*)d_ws;
  float* out = (float*)d_out;
  transpose_cast_k<<<dim3(32,96,4), 256, 0, stream>>>(kf, kb, rf, rb, ws);
  gather_xe_k<<<8192, 256, 0, stream>>>(x, emb, ws);
  make_mask_k<<<64, 256, 0, stream>>>(x, ws);
  xp_gemm_k<<<dim3(128,24,2), 256, 0, stream>>>(bf_, bb, ws);
  zero_ws_k<<<66, 256, 0, stream>>>(ws);   // after xp_gemm: ring slot0 overlays dead KT
  gru_scan_k<<<128, 192, 0, stream>>>(ws, out, bf_, bb);
}

// Round 4
// 7219.347 us; speedup vs baseline: 1.2119x; 1.0439x over previous
//
#include <hip/hip_runtime.h>

typedef __bf16 bf16;
typedef __bf16 bf16x8 __attribute__((ext_vector_type(8)));
typedef __bf16 bf16x4 __attribute__((ext_vector_type(4)));
typedef float f32x4 __attribute__((ext_vector_type(4)));

// ---------------- workspace layout (bytes) ----------------
// Persistent: RT, XP, MASK, BAR, RING. KT/XE are prep-only and overlay the ring.
static constexpr size_t SZ_RT   = 2ull*3072*1024*2;          // rec^T bf16 [2][3072][1024]
static constexpr size_t SZ_XP   = 2ull*16384*3072*2;         // xp bf16 [d][j][t][g][b][16]
static constexpr size_t SZ_MASK = 16384ull*4;                // mask f32 [t][b]
static constexpr size_t HF_CHUNKS = 8256;                    // 8192 used + pad
static constexpr size_t SLOT    = 2ull*HF_CHUNKS*16;         // one ring slot = [d][8256 chunks]
static constexpr size_t OFF_RT   = 0;
static constexpr size_t OFF_XP   = OFF_RT + SZ_RT;
static constexpr size_t OFF_MASK = OFF_XP + SZ_XP;
static constexpr size_t OFF_BAR  = OFF_MASK + SZ_MASK;       // 2 KB barrier region
static constexpr size_t OFF_RING = OFF_BAR + 2048;           // 257 slots (write-once per call)
static constexpr size_t OFF_KT   = OFF_RING;                 // prep-only (dead before ring use)
static constexpr size_t OFF_XE   = OFF_RING + 2ull*3072*1024*2;

__device__ __forceinline__ void async16(void* lds, const void* g) {
  __builtin_amdgcn_global_load_lds((const __attribute__((address_space(1))) unsigned int*)g,
                                   (__attribute__((address_space(3))) unsigned int*)lds,
                                   16, 0, 0);
}

// ---------------- prep kernels ----------------
// Runs AFTER xp_gemm (overlays KT): zero ring slot 0 (initial h) + barrier region.
__global__ void zero_ws_k(char* ws) {
  size_t i = (size_t)blockIdx.x*256 + threadIdx.x;
  if (i < SLOT/16)                  ((uint4*)(ws + OFF_RING))[i] = make_uint4(0u,0u,0u,0u);
  else if (i < SLOT/16 + 128)       ((uint4*)(ws + OFF_BAR))[i - SLOT/16] = make_uint4(0u,0u,0u,0u);
}

// f32 [1024][3072] -> bf16 [3072][1024] (n-major) for MFMA B-fragment loads
__global__ void transpose_cast_k(const float* kf, const float* kb,
                                 const float* rf, const float* rb, char* ws) {
  __shared__ float tile[32][33];
  const int mat = blockIdx.z;
  const float* src = (mat==0)?kf:(mat==1)?kb:(mat==2)?rf:rb;
  bf16* dst = (bf16*)(ws + ((mat<2)?OFF_KT:OFF_RT)) + (size_t)(mat&1)*3072*1024;
  const int k0 = blockIdx.x*32, n0 = blockIdx.y*32;
  const int r = threadIdx.x >> 5, c = threadIdx.x & 31;
  for (int rr = r; rr < 32; rr += 8)
    tile[rr][c] = src[(size_t)(k0+rr)*3072 + n0 + c];
  __syncthreads();
  const int rn = threadIdx.x >> 3, kq = threadIdx.x & 7;
  bf16x4 v;
  #pragma unroll
  for (int ii = 0; ii < 4; ++ii) v[ii] = (bf16)tile[kq*4+ii][rn];
  *(bf16x4*)(dst + (size_t)(n0+rn)*1024 + k0 + kq*4) = v;
}

__global__ void gather_xe_k(const int* x, const float* emb, char* ws) {
  size_t c = (size_t)blockIdx.x*256 + threadIdx.x;   // 16384*128 chunks of 8
  int rowid = (int)(c >> 7); int u8 = (int)(c & 127);
  int t = rowid >> 6, b = rowid & 63;
  int tok = x[b*256 + t];
  const float* e = emb + (size_t)tok*1024 + u8*8;
  float4 a  = *(const float4*)e;
  float4 b2 = *(const float4*)(e+4);
  bf16x8 o;
  o[0]=(bf16)a.x;  o[1]=(bf16)a.y;  o[2]=(bf16)a.z;  o[3]=(bf16)a.w;
  o[4]=(bf16)b2.x; o[5]=(bf16)b2.y; o[6]=(bf16)b2.z; o[7]=(bf16)b2.w;
  *(bf16x8*)((bf16*)(ws+OFF_XE) + (size_t)rowid*1024 + u8*8) = o;
}

__global__ void make_mask_k(const int* x, char* ws) {
  int tid = blockIdx.x*256 + threadIdx.x;            // t*64+b
  int t = tid >> 6, b = tid & 63;
  ((float*)(ws+OFF_MASK))[tid] = (x[b*256+t] != 0) ? 1.0f : 0.0f;
}

// ---------------- xp = xe @ kernel + b_i (both dirs), 128x128 tile ----------------
__global__ __launch_bounds__(256) void xp_gemm_k(const float* bias_f, const float* bias_b, char* ws) {
  __shared__ __align__(16) char smem[16384];         // As 128x32, Bs 128x32 bf16
  const int tid = threadIdx.x, w = tid>>6, l = tid&63;
  const int m0 = blockIdx.x*128, n0 = blockIdx.y*128, d = blockIdx.z;
  const bf16* xe = (const bf16*)(ws + OFF_XE);
  const bf16* Bt = (const bf16*)(ws + OFF_KT) + (size_t)d*3072*1024;
  const float* bias = d ? bias_b : bias_f;           // row 0 = b_i
  const int wm = (w>>1)*64, wn = (w&1)*64;
  const f32x4 fzero = {0.f,0.f,0.f,0.f};
  f32x4 acc[4][4];
  #pragma unroll
  for (int i=0;i<4;++i)
    #pragma unroll
    for (int jj=0;jj<4;++jj) acc[i][jj] = fzero;
  for (int k0 = 0; k0 < 1024; k0 += 32) {
    #pragma unroll
    for (int it = 0; it < 2; ++it) {
      int cc = w*128 + it*64 + l;                    // 0..511
      int row = cc>>2, kp = cc&3;
      async16(smem        + (size_t)(w*128 + it*64)*16, xe + (size_t)(m0+row)*1024 + k0 + kp*8);
      async16(smem + 8192 + (size_t)(w*128 + it*64)*16, Bt + (size_t)(n0+row)*1024 + k0 + kp*8);
    }
    __builtin_amdgcn_s_waitcnt(0);
    __syncthreads();
    const bf16* As = (const bf16*)smem;
    const bf16* Bs = (const bf16*)(smem + 8192);
    bf16x8 bfr[4];
    #pragma unroll
    for (int nt=0;nt<4;++nt)
      bfr[nt] = *(const bf16x8*)(Bs + (wn + nt*16 + (l&15))*32 + (l>>4)*8);
    #pragma unroll
    for (int mt=0;mt<4;++mt) {
      bf16x8 af = *(const bf16x8*)(As + (wm + mt*16 + (l&15))*32 + (l>>4)*8);
      #pragma unroll
      for (int nt=0;nt<4;++nt)
        acc[mt][nt] = __builtin_amdgcn_mfma_f32_16x16x32_bf16(af, bfr[nt], acc[mt][nt], 0,0,0);
    }
    __syncthreads();
  }
  bf16* xp = (bf16*)(ws + OFF_XP);
  #pragma unroll
  for (int nt=0;nt<4;++nt) {
    int n = n0 + wn + nt*16 + (l&15);
    float bv = bias[n];
    int g = n>>10, jj = (n>>4)&63, u = n&15;
    #pragma unroll
    for (int mt=0;mt<4;++mt) {
      #pragma unroll
      for (int r2=0;r2<4;++r2) {
        int m = m0 + wm + mt*16 + (l>>4)*4 + r2;
        int t = m>>6, b = m&63;
        float val = acc[mt][nt][r2] + bv;
        xp[((((size_t)(d*64+jj)*256 + t)*3 + g)*64 + b)*16 + u] = (bf16)val;
      }
    }
  }
}

// ---------------- persistent GRU scan ----------------
// Hierarchical barrier: 8 L0 counter lines (16 arrivals each) -> 1 L1 line (8)
// -> release flag on its OWN line. Pollers only read the flag line, so poll
// traffic never interferes with the arrival RMW chain.
__device__ __forceinline__ void grid_barrier(unsigned* bar, unsigned target) {
  __builtin_amdgcn_s_waitcnt(0);   // all h-frag/out stores globally visible
  __syncthreads();
  if (threadIdx.x == 0) {
    unsigned* c0 = bar + (blockIdx.x & 7)*32;   // 128 B apart
    unsigned* c1 = bar + 8*32;
    unsigned* fl = bar + 9*32;
    unsigned a = __hip_atomic_fetch_add(c0, 1u, __ATOMIC_RELAXED, __HIP_MEMORY_SCOPE_AGENT);
    if ((a & 15u) == 15u) {
      unsigned b = __hip_atomic_fetch_add(c1, 1u, __ATOMIC_RELAXED, __HIP_MEMORY_SCOPE_AGENT);
      if ((b & 7u) == 7u)
        __hip_atomic_store(fl, target, __ATOMIC_RELAXED, __HIP_MEMORY_SCOPE_AGENT);
    }
    while (__hip_atomic_load(fl, __ATOMIC_RELAXED, __HIP_MEMORY_SCOPE_AGENT) < target)
      __builtin_amdgcn_s_sleep(4);
  }
  __syncthreads();
}

// 128 WGs: wg = d*64 + j (j = 16-unit block). 4 waves = K-split 8 ktiles each,
// rec_kernel B-frags pinned in VGPRs. h broadcast through a write-once ring.
__global__ __launch_bounds__(256, 1) void gru_scan_k(char* ws, float* out,
                                                     const float* bias_f, const float* bias_b) {
  __shared__ __align__(16) char lds_h[HF_CHUNKS*16];  // h fragments (129 KB)
  __shared__ float rec_lds[3*1024];                   // [g][b][u16] partial sums (+b_r)
  __shared__ float h_master[1024];                    // f32 h state for this unit block
  __shared__ float br_lds[48];
  const int wg = blockIdx.x;
  const int d = wg >> 6, j = wg & 63;
  const int tid = threadIdx.x, w = tid >> 6, l = tid & 63;
  const bf16* rT    = (const bf16*)(ws + OFF_RT) + (size_t)d*3072*1024;
  const bf16* xp    = (const bf16*)(ws + OFF_XP);
  const float* mask = (const float*)(ws + OFF_MASK);
  char* ring = ws + OFF_RING;
  unsigned* bar = (unsigned*)(ws + OFF_BAR);
  const float* bias = d ? bias_b : bias_f;
  if (tid < 48) br_lds[tid] = bias[3072 + (tid>>4)*1024 + j*16 + (tid&15)];   // b_r
  for (int p = tid; p < 1024; p += 256) h_master[p] = 0.f;
  const int kt0 = w*8;                                // 8 ktiles per wave
  bf16x8 Breg[24];                                    // [gate][kk]
  #pragma unroll
  for (int g = 0; g < 3; ++g)
    #pragma unroll
    for (int kk = 0; kk < 8; ++kk)
      Breg[g*8+kk] = *(const bf16x8*)(rT + (size_t)(g*1024 + j*16 + (l&15))*1024
                                         + (kt0+kk)*32 + (l>>4)*8);
  // epilogue-thread constants + step-0 prefetch
  const int b_ep = tid >> 1, half = tid & 1, u0 = half*8;
  bf16x8 xz_c = {}, xr_c = {}, xh_c = {};
  float m_c = 0.f;
  {
    const int t0 = d ? 255 : 0;
    if (tid < 128) {
      const bf16* xpt = xp + (((size_t)(d*64 + j)*256 + t0)*3)*1024;
      xz_c = *(const bf16x8*)(xpt + b_ep*16 + u0);
      xr_c = *(const bf16x8*)(xpt + 1024 + b_ep*16 + u0);
      xh_c = *(const bf16x8*)(xpt + 2048 + b_ep*16 + u0);
      m_c  = mask[t0*64 + b_ep];
    }
  }
  __syncthreads();
  const f32x4 fzero = {0.f,0.f,0.f,0.f};
  for (int step = 0; step < 256; ++step) {
    const int t = d ? (255 - step) : step;
    // ---- stage h fragments (ring slot = step) into LDS; init rec_lds = b_r meanwhile
    const char* hsrc = ring + (size_t)step*SLOT + (size_t)d*(SLOT/2);
    for (int i = 0; i < 33; ++i) {
      int idx = i*256 + w*64;
      if (idx < 8256)
        async16(lds_h + (size_t)idx*16, hsrc + (size_t)(idx + l)*16);
    }
    for (int p = tid; p < 3072; p += 256)
      rec_lds[p] = br_lds[((p>>10)<<4) | (p&15)];
    __builtin_amdgcn_s_waitcnt(0);
    __syncthreads();
    // ---- GEMM: rec[b][gate-cols] partials over this wave's K-slice
    f32x4 acc[4][3];
    #pragma unroll
    for (int mt=0;mt<4;++mt)
      #pragma unroll
      for (int g=0;g<3;++g) acc[mt][g] = fzero;
    #pragma unroll
    for (int kk = 0; kk < 8; ++kk) {
      const int kt = kt0 + kk;
      #pragma unroll
      for (int mt = 0; mt < 4; ++mt) {
        bf16x8 a = *(const bf16x8*)(lds_h + (size_t)((kt*4 + mt)*64 + l)*16);
        acc[mt][0] = __builtin_amdgcn_mfma_f32_16x16x32_bf16(a, Breg[0*8+kk], acc[mt][0],0,0,0);
        acc[mt][1] = __builtin_amdgcn_mfma_f32_16x16x32_bf16(a, Breg[1*8+kk], acc[mt][1],0,0,0);
        acc[mt][2] = __builtin_amdgcn_mfma_f32_16x16x32_bf16(a, Breg[2*8+kk], acc[mt][2],0,0,0);
      }
    }
    #pragma unroll
    for (int mt = 0; mt < 4; ++mt)
      #pragma unroll
      for (int g = 0; g < 3; ++g)
        #pragma unroll
        for (int r2 = 0; r2 < 4; ++r2) {
          int b = mt*16 + (l>>4)*4 + r2;
          atomicAdd(&rec_lds[g*1024 + b*16 + (l&15)], acc[mt][g][r2]);
        }
    __syncthreads();
    // ---- epilogue: prefetch next xp/mask, gate math, out, next-slot h write
    bf16* hdst = (bf16*)(ring + (size_t)(step+1)*SLOT + (size_t)d*(SLOT/2));
    const bool adder = d ? (t < 128) : (t >= 128);    // later phase adds
    if (tid < 128) {
      // prefetch step+1 (clamped on last step) — latency hidden behind barrier
      const int sn = (step < 255) ? step + 1 : step;
      const int tn = d ? (255 - sn) : sn;
      const bf16* xpn = xp + (((size_t)(d*64 + j)*256 + tn)*3)*1024;
      bf16x8 xz_n = *(const bf16x8*)(xpn + b_ep*16 + u0);
      bf16x8 xr_n = *(const bf16x8*)(xpn + 1024 + b_ep*16 + u0);
      bf16x8 xh_n = *(const bf16x8*)(xpn + 2048 + b_ep*16 + u0);
      float  m_n  = mask[tn*64 + b_ep];
      float hvals[8];
      #pragma unroll
      for (int i = 0; i < 8; ++i) {
        int p = b_ep*16 + u0 + i;
        float z = 1.f/(1.f + __expf(-((float)xz_c[i] + rec_lds[p])));
        float r = 1.f/(1.f + __expf(-((float)xr_c[i] + rec_lds[1024 + p])));
        float pre = (float)xh_c[i] + r*rec_lds[2048 + p];
        pre = fminf(fmaxf(pre, -15.f), 15.f);
        float e2 = __expf(-2.f*pre);
        float hh = (1.f - e2)/(1.f + e2);
        float hold = h_master[p];
        float hnew = z*hold + (1.f - z)*hh;
        float ho = (m_c != 0.f) ? hnew : hold;
        h_master[p] = ho;
        hvals[i] = ho;
      }
      // h-fragment chunk for next step first (this is what other WGs wait on)
      const int kt = j >> 1, q = (j&1)*2 + half, lw = (b_ep&15) | (q<<4), mt = b_ep>>4;
      union { bf16 h8[8]; unsigned long long q2[2]; } pk;
      #pragma unroll
      for (int i = 0; i < 8; ++i) pk.h8[i] = (bf16)hvals[i];
      unsigned long long* hq = (unsigned long long*)(hdst + (size_t)((kt*4 + mt)*64 + lw)*8);
      __hip_atomic_store(hq,     pk.q2[0], __ATOMIC_RELAXED, __HIP_MEMORY_SCOPE_AGENT);
      __hip_atomic_store(hq + 1, pk.q2[1], __ATOMIC_RELAXED, __HIP_MEMORY_SCOPE_AGENT);
      float* op = out + ((size_t)b_ep*256 + t)*1024 + j*16 + u0;
      if (adder) {
        #pragma unroll
        for (int i = 0; i < 8; ++i)
          __hip_atomic_fetch_add(op + i, hvals[i], __ATOMIC_RELAXED, __HIP_MEMORY_SCOPE_AGENT);
      } else {
        #pragma unroll
        for (int i = 0; i < 8; ++i)
          __hip_atomic_store(op + i, hvals[i], __ATOMIC_RELAXED, __HIP_MEMORY_SCOPE_AGENT);
      }
      xz_c = xz_n; xr_c = xr_n; xh_c = xh_n; m_c = m_n;
    }
    if (step < 255) grid_barrier(bar, (unsigned)(step + 1));
  }
}

// ---------------- launch ----------------
extern "C" void kernel_launch(void* const* d_in, const int* in_sizes, int n_in,
                              void* d_out, int out_size, void* d_ws, size_t ws_size,
                              hipStream_t stream) {
  (void)in_sizes; (void)n_in; (void)out_size; (void)ws_size;
  const int*   x   = (const int*)d_in[0];
  const float* emb = (const float*)d_in[1];
  const float* kf  = (const float*)d_in[2];
  const float* rf  = (const float*)d_in[3];
  const float* bf_ = (const float*)d_in[4];
  const float* kb  = (const float*)d_in[5];
  const float* rb  = (const float*)d_in[6];
  const float* bb  = (const float*)d_in[7];
  char* ws = (char*)d_ws;
  float* out = (float*)d_out;
  transpose_cast_k<<<dim3(32,96,4), 256, 0, stream>>>(kf, kb, rf, rb, ws);
  gather_xe_k<<<8192, 256, 0, stream>>>(x, emb, ws);
  make_mask_k<<<64, 256, 0, stream>>>(x, ws);
  xp_gemm_k<<<dim3(128,24,2), 256, 0, stream>>>(bf_, bb, ws);
  zero_ws_k<<<65, 256, 0, stream>>>(ws);   // after xp_gemm: ring slot0 overlays dead KT
  gru_scan_k<<<128, 256, 0, stream>>>(ws, out, bf_, bb);
}